// Round 1
// baseline (6329.247 us; speedup 1.0000x reference)
//
#include <hip/hip_runtime.h>

#define THREADS 256
#define DFEAT 64
#define SCAN_CHUNK 2048

struct EdgeT { int c; float w; };

// ---------------- CSR build ----------------

__global__ void count_deg_kernel(const int* __restrict__ ei, int E,
                                 int* __restrict__ deg_r, int* __restrict__ deg_c) {
    int e = blockIdx.x * blockDim.x + threadIdx.x;
    if (e < E) {
        atomicAdd(&deg_r[ei[e]], 1);
        atomicAdd(&deg_c[ei[e + E]], 1);
    }
}

__global__ void scan_phase1(const int* __restrict__ deg, int n, int* __restrict__ bsums) {
    int base = blockIdx.x * SCAN_CHUNK;
    int sum = 0;
    for (int i = threadIdx.x; i < SCAN_CHUNK; i += THREADS) {
        int idx = base + i;
        if (idx < n) sum += deg[idx];
    }
    __shared__ int wsum[4];
    int lane = threadIdx.x & 63, wid = threadIdx.x >> 6;
    for (int off = 32; off; off >>= 1) sum += __shfl_down(sum, off);
    if (lane == 0) wsum[wid] = sum;
    __syncthreads();
    if (threadIdx.x == 0)
        bsums[blockIdx.x] = wsum[0] + wsum[1] + wsum[2] + wsum[3];
}

__global__ void scan_phase2(int* __restrict__ bsums, int nb,
                            int* __restrict__ row_ptr, int N, int E) {
    if (blockIdx.x == 0 && threadIdx.x == 0) {
        int acc = 0;
        for (int b = 0; b < nb; ++b) { int v = bsums[b]; bsums[b] = acc; acc += v; }
        row_ptr[N] = E;
    }
}

__global__ void scan_phase3(const int* __restrict__ deg, int n, const int* __restrict__ bsums,
                            int* __restrict__ row_ptr, int* __restrict__ cursor) {
    int base = blockIdx.x * SCAN_CHUNK;
    int tbase = base + threadIdx.x * 8;
    int my[8]; int s = 0;
#pragma unroll
    for (int j = 0; j < 8; ++j) { int idx = tbase + j; my[j] = (idx < n) ? deg[idx] : 0; s += my[j]; }
    int lane = threadIdx.x & 63, wid = threadIdx.x >> 6;
    int v = s;
    for (int off = 1; off < 64; off <<= 1) { int t = __shfl_up(v, off); if (lane >= off) v += t; }
    __shared__ int wsum[4];
    if (lane == 63) wsum[wid] = v;
    __syncthreads();
    int woff = 0;
    for (int w = 0; w < wid; ++w) woff += wsum[w];
    int acc = bsums[blockIdx.x] + woff + (v - s);
#pragma unroll
    for (int j = 0; j < 8; ++j) {
        int idx = tbase + j;
        if (idx < n) { row_ptr[idx] = acc; cursor[idx] = acc; }
        acc += my[j];
    }
}

__global__ void build_csr_kernel(const int* __restrict__ ei, int E,
                                 const int* __restrict__ deg_r, const int* __restrict__ deg_c,
                                 const int* __restrict__ mask,
                                 int* __restrict__ cursor,
                                 EdgeT* __restrict__ e1, EdgeT* __restrict__ e2) {
    int e = blockIdx.x * blockDim.x + threadIdx.x;
    if (e >= E) return;
    int r = ei[e], c = ei[e + E];
    float w = rsqrtf((float)deg_r[r]) * rsqrtf((float)deg_c[c]);
    int p = atomicAdd(&cursor[r], 1);
    EdgeT t2; t2.c = c; t2.w = w;                       e2[p] = t2;
    EdgeT t1; t1.c = c; t1.w = mask[c] ? w : 0.0f;      e1[p] = t1;
}

// ---------------- elementwise: k <- r + c*k (in place) ----------------

__global__ void axpy_inplace(float* __restrict__ k, const float* __restrict__ r,
                             float cin, int n4) {
    int i = blockIdx.x * blockDim.x + threadIdx.x;
    int stride = gridDim.x * blockDim.x;
    const float4* r4 = (const float4*)r;
    float4* k4 = (float4*)k;
    for (; i < n4; i += stride) {
        float4 a = r4[i], b = k4[i];
        b.x = a.x + cin * b.x; b.y = a.y + cin * b.y;
        b.z = a.z + cin * b.z; b.w = a.w + cin * b.w;
        k4[i] = b;
    }
}

// ---------------- SpMM: one wave per row, lane = feature ----------------

__global__ __launch_bounds__(256) void spmm_plain(const int* __restrict__ row_ptr,
                                                  const EdgeT* __restrict__ edges,
                                                  const float* __restrict__ x,
                                                  float* __restrict__ out, int n) {
    int row = blockIdx.x * 4 + (threadIdx.x >> 6);
    if (row >= n) return;
    int lane = threadIdx.x & 63;
    int s = row_ptr[row], e = row_ptr[row + 1];
    float acc = 0.f;
    for (int j = s; j < e; ++j) {
        EdgeT ed = edges[j];
        acc += ed.w * x[(size_t)ed.c * DFEAT + lane];
    }
    out[(size_t)row * DFEAT + lane] = acc;
}

template <bool INIT>
__global__ __launch_bounds__(256) void spmm_hop2(const int* __restrict__ row_ptr,
                                                 const EdgeT* __restrict__ edges,
                                                 const float* __restrict__ t1,
                                                 const float* __restrict__ r_prev,
                                                 float acc_coef,
                                                 float* __restrict__ k,
                                                 float* __restrict__ out_next, int n) {
    int row = blockIdx.x * 4 + (threadIdx.x >> 6);
    if (row >= n) return;
    int lane = threadIdx.x & 63;
    int s = row_ptr[row], e = row_ptr[row + 1];
    float acc = 0.f;
    for (int j = s; j < e; ++j) {
        EdgeT ed = edges[j];
        acc += ed.w * t1[(size_t)ed.c * DFEAT + lane];
    }
    float knew = -acc;
    size_t idx = (size_t)row * DFEAT + lane;
    k[idx] = knew;
    if (INIT) out_next[idx] = r_prev[idx] + acc_coef * knew;
    else      out_next[idx] += acc_coef * knew;
}

// ---------------- host ----------------

extern "C" void kernel_launch(void* const* d_in, const int* in_sizes, int n_in,
                              void* d_out, int out_size, void* d_ws, size_t ws_size,
                              hipStream_t stream) {
    const float* r0  = (const float*)d_in[0];
    const int*   ei  = (const int*)d_in[1];
    const int*   msk = (const int*)d_in[2];
    float* out = (float*)d_out;

    const int N = in_sizes[2];
    const int E = in_sizes[1] / 2;
    const size_t ND = (size_t)N * DFEAT;

    // workspace carve-out (256B aligned)
    char* ws = (char*)d_ws;
    size_t off = 0;
    auto carve = [&](size_t bytes) -> void* {
        off = (off + 255) & ~(size_t)255;
        void* p = ws + off;
        off += bytes;
        return p;
    };
    int*   deg_r   = (int*)carve((size_t)N * 4);
    int*   deg_c   = (int*)carve((size_t)N * 4);
    int*   row_ptr = (int*)carve((size_t)(N + 1) * 4);
    int*   cursor  = (int*)carve((size_t)N * 4);
    int*   bsums   = (int*)carve(1024 * 4);
    EdgeT* e1      = (EdgeT*)carve((size_t)E * sizeof(EdgeT));
    EdgeT* e2      = (EdgeT*)carve((size_t)E * sizeof(EdgeT));
    float* t1      = (float*)carve(ND * 4);
    float* kbuf    = (float*)carve(ND * 4);

    // ---- CSR build ----
    hipMemsetAsync(deg_r, 0, (size_t)N * 4, stream);
    hipMemsetAsync(deg_c, 0, (size_t)N * 4, stream);
    int gE = (E + THREADS - 1) / THREADS;
    count_deg_kernel<<<gE, THREADS, 0, stream>>>(ei, E, deg_r, deg_c);
    int nb = (N + SCAN_CHUNK - 1) / SCAN_CHUNK;
    scan_phase1<<<nb, THREADS, 0, stream>>>(deg_r, N, bsums);
    scan_phase2<<<1, 64, 0, stream>>>(bsums, nb, row_ptr, N, E);
    scan_phase3<<<nb, THREADS, 0, stream>>>(deg_r, N, bsums, row_ptr, cursor);
    build_csr_kernel<<<gE, THREADS, 0, stream>>>(ei, E, deg_r, deg_c, msk, cursor, e1, e2);

    // ---- out[0] = r0 ----
    hipMemcpyAsync(out, r0, ND * 4, hipMemcpyDeviceToDevice, stream);

    // ---- RK4 steps ----
    const float DT = 0.2f;
    const float cin[4] = {0.f, 0.5f * DT, 0.5f * DT, DT};
    const float ac[4]  = {DT / 6.f, 2.f * DT / 6.f, 2.f * DT / 6.f, DT / 6.f};
    int gridR = (N + 3) / 4;

    for (int s = 0; s < 5; ++s) {
        const float* r  = out + (size_t)s * ND;
        float*       rn = out + (size_t)(s + 1) * ND;
        for (int st = 0; st < 4; ++st) {
            const float* src;
            if (st == 0) {
                src = r;
            } else {
                axpy_inplace<<<2048, THREADS, 0, stream>>>(kbuf, r, cin[st], (int)(ND / 4));
                src = kbuf;
            }
            spmm_plain<<<gridR, THREADS, 0, stream>>>(row_ptr, e1, src, t1, N);
            if (st == 0)
                spmm_hop2<true><<<gridR, THREADS, 0, stream>>>(row_ptr, e2, t1, r, ac[st], kbuf, rn, N);
            else
                spmm_hop2<false><<<gridR, THREADS, 0, stream>>>(row_ptr, e2, t1, r, ac[st], kbuf, rn, N);
        }
    }
}

// Round 2
// 2777.088 us; speedup vs baseline: 2.2791x; 2.2791x over previous
//
#include <hip/hip_runtime.h>

#define THREADS 256
#define SCAN_CHUNK 2048
#define DT_C 0.2f

__device__ __forceinline__ unsigned pack_bf16(float x, float y) {
    unsigned xb = __float_as_uint(x);
    unsigned yb = __float_as_uint(y);
    xb = (xb + 0x7fffu + ((xb >> 16) & 1u)) >> 16;
    yb = (yb + 0x7fffu + ((yb >> 16) & 1u)) >> 16;
    return xb | (yb << 16);
}

// ---------------- CSR build ----------------

__global__ void count_deg_kernel(const int* __restrict__ ei, int E,
                                 int* __restrict__ deg_r, int* __restrict__ deg_c) {
    int e = blockIdx.x * blockDim.x + threadIdx.x;
    if (e < E) {
        atomicAdd(&deg_r[ei[e]], 1);
        atomicAdd(&deg_c[ei[e + E]], 1);
    }
}

__global__ void scan_phase1(const int* __restrict__ deg, int n, int* __restrict__ bsums) {
    int base = blockIdx.x * SCAN_CHUNK;
    int sum = 0;
    for (int i = threadIdx.x; i < SCAN_CHUNK; i += THREADS) {
        int idx = base + i;
        if (idx < n) sum += deg[idx];
    }
    __shared__ int wsum[4];
    int lane = threadIdx.x & 63, wid = threadIdx.x >> 6;
    for (int off = 32; off; off >>= 1) sum += __shfl_down(sum, off);
    if (lane == 0) wsum[wid] = sum;
    __syncthreads();
    if (threadIdx.x == 0)
        bsums[blockIdx.x] = wsum[0] + wsum[1] + wsum[2] + wsum[3];
}

__global__ void scan_phase2(int* __restrict__ bsums, int nb,
                            int* __restrict__ row_ptr, int N, int E) {
    if (blockIdx.x == 0 && threadIdx.x == 0) {
        int acc = 0;
        for (int b = 0; b < nb; ++b) { int v = bsums[b]; bsums[b] = acc; acc += v; }
        row_ptr[N] = E;
    }
}

__global__ void scan_phase3(const int* __restrict__ deg, int n, const int* __restrict__ bsums,
                            int* __restrict__ row_ptr, int* __restrict__ cursor) {
    int base = blockIdx.x * SCAN_CHUNK;
    int tbase = base + threadIdx.x * 8;
    int my[8]; int s = 0;
#pragma unroll
    for (int j = 0; j < 8; ++j) { int idx = tbase + j; my[j] = (idx < n) ? deg[idx] : 0; s += my[j]; }
    int lane = threadIdx.x & 63, wid = threadIdx.x >> 6;
    int v = s;
    for (int off = 1; off < 64; off <<= 1) { int t = __shfl_up(v, off); if (lane >= off) v += t; }
    __shared__ int wsum[4];
    if (lane == 63) wsum[wid] = v;
    __syncthreads();
    int woff = 0;
    for (int w = 0; w < wid; ++w) woff += wsum[w];
    int acc = bsums[blockIdx.x] + woff + (v - s);
#pragma unroll
    for (int j = 0; j < 8; ++j) {
        int idx = tbase + j;
        if (idx < n) { row_ptr[idx] = acc; cursor[idx] = acc; }
        acc += my[j];
    }
}

__global__ void make_dinv(const int* __restrict__ deg_r, const int* __restrict__ deg_c,
                          const int* __restrict__ mask,
                          float* __restrict__ dr, float* __restrict__ dc,
                          float* __restrict__ dcm, int n) {
    int i = blockIdx.x * blockDim.x + threadIdx.x;
    if (i < n) {
        int a = deg_r[i];
        dr[i] = a > 0 ? rsqrtf((float)a) : 0.f;
        int b = deg_c[i];
        float v = b > 0 ? rsqrtf((float)b) : 0.f;
        dc[i] = v;
        dcm[i] = mask[i] ? v : 0.f;
    }
}

__global__ void build_csr_kernel(const int* __restrict__ ei, int E,
                                 int* __restrict__ cursor, int* __restrict__ colv) {
    int e = blockIdx.x * blockDim.x + threadIdx.x;
    if (e < E) {
        int r = ei[e], c = ei[e + E];
        colv[atomicAdd(&cursor[r], 1)] = c;
    }
}

// ---------------- init: out[0] = r0 ; xb = bf16(r0) ----------------

__global__ void init_kernel(const float* __restrict__ r0, float* __restrict__ out0,
                            unsigned* __restrict__ xb, int n4) {
    int i = blockIdx.x * blockDim.x + threadIdx.x;
    int stride = gridDim.x * blockDim.x;
    const float4* r4 = (const float4*)r0;
    float4* o4 = (float4*)out0;
    for (; i < n4; i += stride) {
        float4 a = r4[i];
        o4[i] = a;
        xb[2 * i]     = pack_bf16(a.x, a.y);
        xb[2 * i + 1] = pack_bf16(a.z, a.w);
    }
}

// ---------------- SpMM hop 1: t1b = bf16( dr[row] * sum dcm[col]*xb[col] ) ----------------
// one wave per row; half-wave per edge (32 lanes x uint = 128B bf16 row); lane handles
// features 2*hl, 2*hl+1. Unroll 2 (4 edges in flight per wave).

__global__ __launch_bounds__(256) void spmm_h1(const int* __restrict__ row_ptr,
                                               const int* __restrict__ cols,
                                               const float* __restrict__ dcm,
                                               const float* __restrict__ dr_arr,
                                               const unsigned* __restrict__ xb,
                                               unsigned* __restrict__ t1b, int n) {
    int row = blockIdx.x * 4 + (threadIdx.x >> 6);
    if (row >= n) return;
    int l = threadIdx.x & 63, h = l >> 5, hl = l & 31;
    int s = row_ptr[row], e = row_ptr[row + 1];
    float a0 = 0.f, a1 = 0.f;
    int j = s + h;
    for (; j + 2 < e; j += 4) {
        int c0 = cols[j], c1 = cols[j + 2];
        float w0 = dcm[c0], w1 = dcm[c1];
        unsigned u0 = xb[c0 * 32 + hl], u1 = xb[c1 * 32 + hl];
        a0 += w0 * __uint_as_float(u0 << 16) + w1 * __uint_as_float(u1 << 16);
        a1 += w0 * __uint_as_float(u0 & 0xffff0000u) + w1 * __uint_as_float(u1 & 0xffff0000u);
    }
    if (j < e) {
        int c0 = cols[j];
        float w0 = dcm[c0];
        unsigned u0 = xb[c0 * 32 + hl];
        a0 += w0 * __uint_as_float(u0 << 16);
        a1 += w0 * __uint_as_float(u0 & 0xffff0000u);
    }
    a0 += __shfl_xor(a0, 32);
    a1 += __shfl_xor(a1, 32);
    if (l < 32) {
        float dr = dr_arr[row];
        t1b[row * 32 + hl] = pack_bf16(dr * a0, dr * a1);
    }
}

// ---------------- SpMM hop 2 + fused RK4 epilogue ----------------
// k = -dr[row] * sum dc[col]*t1b[col]
// ST==0: rn = r + ac*k ; xb = bf16(r + cin*k)
// ST==1: rn += ac*k    ; xb = bf16(r + cin*k)
// ST==3: rn += ac*k    ; xb = bf16(rn_final)

template <int ST>
__global__ __launch_bounds__(256) void spmm_h2(const int* __restrict__ row_ptr,
                                               const int* __restrict__ cols,
                                               const float* __restrict__ dc,
                                               const float* __restrict__ dr_arr,
                                               const unsigned* __restrict__ t1b,
                                               const float* __restrict__ r_prev,
                                               float* __restrict__ rn,
                                               unsigned* __restrict__ xb,
                                               float ac, float cin, int n) {
    int row = blockIdx.x * 4 + (threadIdx.x >> 6);
    if (row >= n) return;
    int l = threadIdx.x & 63, h = l >> 5, hl = l & 31;
    int s = row_ptr[row], e = row_ptr[row + 1];
    float a0 = 0.f, a1 = 0.f;
    int j = s + h;
    for (; j + 2 < e; j += 4) {
        int c0 = cols[j], c1 = cols[j + 2];
        float w0 = dc[c0], w1 = dc[c1];
        unsigned u0 = t1b[c0 * 32 + hl], u1 = t1b[c1 * 32 + hl];
        a0 += w0 * __uint_as_float(u0 << 16) + w1 * __uint_as_float(u1 << 16);
        a1 += w0 * __uint_as_float(u0 & 0xffff0000u) + w1 * __uint_as_float(u1 & 0xffff0000u);
    }
    if (j < e) {
        int c0 = cols[j];
        float w0 = dc[c0];
        unsigned u0 = t1b[c0 * 32 + hl];
        a0 += w0 * __uint_as_float(u0 << 16);
        a1 += w0 * __uint_as_float(u0 & 0xffff0000u);
    }
    a0 += __shfl_xor(a0, 32);
    a1 += __shfl_xor(a1, 32);
    if (l < 32) {
        float dr = dr_arr[row];
        float k0 = -dr * a0, k1 = -dr * a1;
        int idx = row * 32 + hl;
        const float2* r2 = (const float2*)r_prev;
        float2* rn2 = (float2*)rn;
        if (ST == 0) {
            float2 rv = r2[idx];
            rn2[idx] = make_float2(rv.x + ac * k0, rv.y + ac * k1);
            xb[idx] = pack_bf16(rv.x + cin * k0, rv.y + cin * k1);
        } else if (ST == 1) {
            float2 rv = r2[idx];
            float2 p = rn2[idx];
            rn2[idx] = make_float2(p.x + ac * k0, p.y + ac * k1);
            xb[idx] = pack_bf16(rv.x + cin * k0, rv.y + cin * k1);
        } else {
            float2 p = rn2[idx];
            p.x += ac * k0; p.y += ac * k1;
            rn2[idx] = p;
            xb[idx] = pack_bf16(p.x, p.y);
        }
    }
}

// ---------------- host ----------------

extern "C" void kernel_launch(void* const* d_in, const int* in_sizes, int n_in,
                              void* d_out, int out_size, void* d_ws, size_t ws_size,
                              hipStream_t stream) {
    const float* r0  = (const float*)d_in[0];
    const int*   ei  = (const int*)d_in[1];
    const int*   msk = (const int*)d_in[2];
    float* out = (float*)d_out;

    const int N = in_sizes[2];
    const int E = in_sizes[1] / 2;
    const size_t ND = (size_t)N * 64;

    char* ws = (char*)d_ws;
    size_t off = 0;
    auto carve = [&](size_t bytes) -> void* {
        off = (off + 255) & ~(size_t)255;
        void* p = ws + off;
        off += bytes;
        return p;
    };
    int*      deg_r   = (int*)carve((size_t)N * 4);
    int*      deg_c   = (int*)carve((size_t)N * 4);
    int*      row_ptr = (int*)carve((size_t)(N + 1) * 4);
    int*      cursor  = (int*)carve((size_t)N * 4);
    int*      bsums   = (int*)carve(1024 * 4);
    float*    dr      = (float*)carve((size_t)N * 4);
    float*    dc      = (float*)carve((size_t)N * 4);
    float*    dcm     = (float*)carve((size_t)N * 4);
    int*      colv    = (int*)carve((size_t)E * 4);
    unsigned* xb      = (unsigned*)carve((size_t)N * 32 * 4);
    unsigned* t1b     = (unsigned*)carve((size_t)N * 32 * 4);

    // ---- CSR build ----
    hipMemsetAsync(deg_r, 0, (size_t)N * 4, stream);
    hipMemsetAsync(deg_c, 0, (size_t)N * 4, stream);
    int gE = (E + THREADS - 1) / THREADS;
    count_deg_kernel<<<gE, THREADS, 0, stream>>>(ei, E, deg_r, deg_c);
    int nb = (N + SCAN_CHUNK - 1) / SCAN_CHUNK;
    scan_phase1<<<nb, THREADS, 0, stream>>>(deg_r, N, bsums);
    scan_phase2<<<1, 64, 0, stream>>>(bsums, nb, row_ptr, N, E);
    scan_phase3<<<nb, THREADS, 0, stream>>>(deg_r, N, bsums, row_ptr, cursor);
    make_dinv<<<(N + THREADS - 1) / THREADS, THREADS, 0, stream>>>(deg_r, deg_c, msk, dr, dc, dcm, N);
    build_csr_kernel<<<gE, THREADS, 0, stream>>>(ei, E, cursor, colv);

    // ---- out[0] = r0 ; xb = bf16(r0) ----
    init_kernel<<<2048, THREADS, 0, stream>>>(r0, out, xb, (int)(ND / 4));

    // ---- RK4 steps ----
    const float ac[4]  = {DT_C / 6.f, 2.f * DT_C / 6.f, 2.f * DT_C / 6.f, DT_C / 6.f};
    const float cin[4] = {0.5f * DT_C, 0.5f * DT_C, DT_C, 0.f};  // cin used by epilogue of stage st (src for st+1)
    int gridR = (N + 3) / 4;

    for (int s = 0; s < 5; ++s) {
        const float* r  = out + (size_t)s * ND;
        float*       rn = out + (size_t)(s + 1) * ND;
        for (int st = 0; st < 4; ++st) {
            spmm_h1<<<gridR, THREADS, 0, stream>>>(row_ptr, colv, dcm, dr, xb, t1b, N);
            if (st == 0)
                spmm_h2<0><<<gridR, THREADS, 0, stream>>>(row_ptr, colv, dc, dr, t1b, r, rn, xb, ac[st], cin[st], N);
            else if (st == 3)
                spmm_h2<3><<<gridR, THREADS, 0, stream>>>(row_ptr, colv, dc, dr, t1b, r, rn, xb, ac[st], cin[st], N);
            else
                spmm_h2<1><<<gridR, THREADS, 0, stream>>>(row_ptr, colv, dc, dr, t1b, r, rn, xb, ac[st], cin[st], N);
        }
    }
}